// Round 3
// baseline (5379.226 us; speedup 1.0000x reference)
//
#include <hip/hip_runtime.h>

#define RELS 4
#define NGRAPH 256

static inline size_t alignup(size_t x) { return (x + 255) & ~(size_t)255; }

// ---------------------------------------------------------------------------
// Count edges per (dst, relation): cnt[dst*R + et] += 1
// ---------------------------------------------------------------------------
__global__ void count_kernel(const int* __restrict__ dst, const int* __restrict__ et,
                             float* __restrict__ cnt, int E)
{
    int e = blockIdx.x * blockDim.x + threadIdx.x;
    if (e < E) {
        unsafeAtomicAdd(&cnt[dst[e] * RELS + et[e]], 1.0f);
    }
}

// ---------------------------------------------------------------------------
// Scatter-add features into per-(node,relation) accumulator.
// Lane-per-channel: IN consecutive lanes handle one edge's IN channels,
// so atomic addresses are consecutive within each group (L2 locality).
// ---------------------------------------------------------------------------
template<int IN>
__global__ void scatter_kernel(const float* __restrict__ feat,
                               const int* __restrict__ src,
                               const int* __restrict__ dst,
                               const int* __restrict__ et,
                               float* __restrict__ s, int E)
{
    constexpr int SH = (IN == 16) ? 4 : 5;
    int i = blockIdx.x * blockDim.x + threadIdx.x;
    int total = E * IN;
    if (i >= total) return;
    int e = i >> SH;
    int k = i & (IN - 1);
    float v = feat[src[e] * IN + k];
    unsafeAtomicAdd(&s[(dst[e] * RELS + et[e]) * IN + k], v);
}

// ---------------------------------------------------------------------------
// Dense per-node transform:
//   out[i] = bias + hin[i] @ root + sum_r (s[i,r]/max(cnt[i,r],1)) @ W_r
// Optional ReLU; optional fused segment-max pool. Pooling is hierarchical:
// LDS pre-reduction per block (batch is sorted, so a block of 256 nodes spans
// ~2 graphs) then a handful of global atomics per block.
// ---------------------------------------------------------------------------
template<int IN, int OUT, bool RELU, bool POOL>
__global__ __launch_bounds__(256)
void transform_kernel(const float* __restrict__ s, const float* __restrict__ cnt,
                      const float* __restrict__ hin,
                      const float* __restrict__ W, const float* __restrict__ root,
                      const float* __restrict__ bias,
                      float* __restrict__ hout, unsigned* __restrict__ gpool,
                      const int* __restrict__ batch, int n)
{
    constexpr int WSZ = RELS * IN * OUT;   // relation weights
    constexpr int RSZ = IN * OUT;          // root weights
    constexpr int NSLOT = 8;               // graph slots per block (POOL only)
    __shared__ float sW[WSZ + RSZ + OUT];
    for (int i = threadIdx.x; i < WSZ; i += 256) sW[i] = W[i];
    for (int i = threadIdx.x; i < RSZ; i += 256) sW[WSZ + i] = root[i];
    for (int i = threadIdx.x; i < OUT; i += 256) sW[WSZ + RSZ + i] = bias[i];

    int node = (int)blockIdx.x * 256 + (int)threadIdx.x;
    bool active = node < n;

    if constexpr (!POOL) {
        __syncthreads();
        if (!active) return;
    }

    const float4* sWv = (const float4*)sW;
    float4 acc[OUT / 4];

    __shared__ unsigned pool_lds[POOL ? NSLOT * OUT : 1];
    int g = 0, g0 = 0;
    if constexpr (POOL) {
        for (int i = threadIdx.x; i < NSLOT * OUT; i += 256) pool_lds[i] = 0u;
        int first = (int)blockIdx.x * 256;
        if (first > n - 1) first = n - 1;
        g0 = batch[first];
        if (active) g = batch[node];
        __syncthreads();
    }

    if (active) {
        #pragma unroll
        for (int o = 0; o < OUT / 4; ++o) acc[o] = sWv[(WSZ + RSZ) / 4 + o];

        // root term: hin[node] @ root
        const float4* hv = (const float4*)(hin + (size_t)node * IN);
        #pragma unroll
        for (int k4 = 0; k4 < IN / 4; ++k4) {
            float4 xv = hv[k4];
            #pragma unroll
            for (int kk = 0; kk < 4; ++kk) {
                float x1 = (&xv.x)[kk];
                int k = k4 * 4 + kk;
                #pragma unroll
                for (int o = 0; o < OUT / 4; ++o) {
                    float4 w = sWv[(WSZ + k * OUT) / 4 + o];
                    acc[o].x += x1 * w.x; acc[o].y += x1 * w.y;
                    acc[o].z += x1 * w.z; acc[o].w += x1 * w.w;
                }
            }
        }

        // relation terms
        #pragma unroll
        for (int r = 0; r < RELS; ++r) {
            float c = cnt[node * RELS + r];
            float nrm = 1.0f / fmaxf(c, 1.0f);
            const float4* sv = (const float4*)(s + ((size_t)node * RELS + r) * IN);
            #pragma unroll
            for (int k4 = 0; k4 < IN / 4; ++k4) {
                float4 mv = sv[k4];
                mv.x *= nrm; mv.y *= nrm; mv.z *= nrm; mv.w *= nrm;
                #pragma unroll
                for (int kk = 0; kk < 4; ++kk) {
                    float m1 = (&mv.x)[kk];
                    int k = k4 * 4 + kk;
                    #pragma unroll
                    for (int o = 0; o < OUT / 4; ++o) {
                        float4 w = sWv[((r * IN + k) * OUT) / 4 + o];
                        acc[o].x += m1 * w.x; acc[o].y += m1 * w.y;
                        acc[o].z += m1 * w.z; acc[o].w += m1 * w.w;
                    }
                }
            }
        }

        if (RELU) {
            #pragma unroll
            for (int o = 0; o < OUT / 4; ++o) {
                acc[o].x = fmaxf(acc[o].x, 0.f); acc[o].y = fmaxf(acc[o].y, 0.f);
                acc[o].z = fmaxf(acc[o].z, 0.f); acc[o].w = fmaxf(acc[o].w, 0.f);
            }
        }
    }

    if constexpr (!POOL) {
        float4* ho = (float4*)(hout + (size_t)node * OUT);
        #pragma unroll
        for (int o = 0; o < OUT / 4; ++o) ho[o] = acc[o];
    } else {
        if (active) {
            int g_local = g - g0;
            #pragma unroll
            for (int o = 0; o < OUT / 4; ++o) {
                #pragma unroll
                for (int kk = 0; kk < 4; ++kk) {
                    float f = (&acc[o].x)[kk];
                    unsigned u = __float_as_uint(f);
                    u = (u & 0x80000000u) ? ~u : (u | 0x80000000u);
                    int ch = o * 4 + kk;
                    if (g_local < NSLOT) atomicMax(&pool_lds[g_local * OUT + ch], u);
                    else                 atomicMax(&gpool[g * OUT + ch], u);
                }
            }
        }
        __syncthreads();
        // flush LDS tile: <= NSLOT*OUT global atomics per block
        for (int i = threadIdx.x; i < NSLOT * OUT; i += 256) {
            unsigned v = pool_lds[i];
            if (v) {
                int slot = i / OUT, ch = i % OUT;
                atomicMax(&gpool[(g0 + slot) * OUT + ch], v);
            }
        }
    }
}

// ---------------------------------------------------------------------------
// MLP head: [G,64] -> 128 (relu) -> 256 (relu) -> 51 -> softmax. 1 block/graph.
// ---------------------------------------------------------------------------
__global__ __launch_bounds__(256)
void mlp_kernel(const unsigned* __restrict__ gpool,
                const float* __restrict__ Wf1, const float* __restrict__ bf1,
                const float* __restrict__ Wh,  const float* __restrict__ bh,
                const float* __restrict__ Wl,  const float* __restrict__ bl,
                float* __restrict__ out)
{
    __shared__ float gin[64];
    __shared__ float f1[128];
    __shared__ float f2[256];
    __shared__ float lg[51];
    int g = blockIdx.x, t = threadIdx.x;

    if (t < 64) {
        unsigned u = gpool[g * 64 + t];
        u = (u & 0x80000000u) ? (u ^ 0x80000000u) : ~u;   // unmap
        gin[t] = __uint_as_float(u);
    }
    __syncthreads();

    if (t < 128) {
        float a = bf1[t];
        #pragma unroll 8
        for (int k = 0; k < 64; ++k) a += gin[k] * Wf1[k * 128 + t];
        f1[t] = fmaxf(a, 0.f);
    }
    __syncthreads();

    {
        float a = bh[t];
        #pragma unroll 8
        for (int k = 0; k < 128; ++k) a += f1[k] * Wh[k * 256 + t];
        f2[t] = fmaxf(a, 0.f);
    }
    __syncthreads();

    if (t < 51) {
        float a = bl[t];
        #pragma unroll 8
        for (int k = 0; k < 256; ++k) a += f2[k] * Wl[k * 51 + t];
        lg[t] = a;
    }
    __syncthreads();

    if (t == 0) {
        float m = lg[0];
        for (int i = 1; i < 51; ++i) m = fmaxf(m, lg[i]);
        float ssum = 0.f;
        for (int i = 0; i < 51; ++i) { float e = __expf(lg[i] - m); lg[i] = e; ssum += e; }
        float inv = 1.0f / ssum;
        for (int i = 0; i < 51; ++i) out[g * 51 + i] = lg[i] * inv;
    }
}

// ---------------------------------------------------------------------------
extern "C" void kernel_launch(void* const* d_in, const int* in_sizes, int n_in,
                              void* d_out, int out_size, void* d_ws, size_t ws_size,
                              hipStream_t stream)
{
    const float* x    = (const float*)d_in[0];
    const int*   ei   = (const int*)d_in[1];
    const int*   et   = (const int*)d_in[2];
    const int*   batch= (const int*)d_in[3];
    const float* W1   = (const float*)d_in[4];
    const float* r1   = (const float*)d_in[5];
    const float* b1   = (const float*)d_in[6];
    const float* W2   = (const float*)d_in[7];
    const float* r2   = (const float*)d_in[8];
    const float* b2   = (const float*)d_in[9];
    const float* W3   = (const float*)d_in[10];
    const float* r3   = (const float*)d_in[11];
    const float* b3   = (const float*)d_in[12];
    const float* Wf1  = (const float*)d_in[13];
    const float* bf1  = (const float*)d_in[14];
    const float* Wh   = (const float*)d_in[15];
    const float* bh   = (const float*)d_in[16];
    const float* Wl   = (const float*)d_in[17];
    const float* bl   = (const float*)d_in[18];

    const int N = in_sizes[0] / 16;
    const int E = in_sizes[2];
    const int* srcp = ei;
    const int* dstp = ei + E;

    char* ws = (char*)d_ws;
    size_t off = 0;
    float*    s     = (float*)(ws + off);   off += alignup((size_t)N * RELS * 32 * 4);
    float*    cnt   = (float*)(ws + off);   off += alignup((size_t)N * RELS * 4);
    float*    h1    = (float*)(ws + off);   off += alignup((size_t)N * 16 * 4);
    float*    h2    = (float*)(ws + off);   off += alignup((size_t)N * 32 * 4);
    unsigned* gpool = (unsigned*)(ws + off); off += alignup((size_t)NGRAPH * 64 * 4);
    (void)ws_size; (void)n_in; (void)out_size;

    // zero accumulators (stream-ordered, capture-safe)
    (void)hipMemsetAsync(cnt, 0, (size_t)N * RELS * 4, stream);
    (void)hipMemsetAsync(gpool, 0, (size_t)NGRAPH * 64 * 4, stream);
    (void)hipMemsetAsync(s, 0, (size_t)N * RELS * 16 * 4, stream);

    count_kernel<<<(E + 255) / 256, 256, 0, stream>>>(dstp, et, cnt, E);

    // ---- layer 1: 16 -> 16, relu
    scatter_kernel<16><<<(E * 16 + 255) / 256, 256, 0, stream>>>(x, srcp, dstp, et, s, E);
    transform_kernel<16, 16, true, false><<<(N + 255) / 256, 256, 0, stream>>>(
        s, cnt, x, W1, r1, b1, h1, nullptr, nullptr, N);

    // ---- layer 2: 16 -> 32, relu
    (void)hipMemsetAsync(s, 0, (size_t)N * RELS * 16 * 4, stream);
    scatter_kernel<16><<<(E * 16 + 255) / 256, 256, 0, stream>>>(h1, srcp, dstp, et, s, E);
    transform_kernel<16, 32, true, false><<<(N + 255) / 256, 256, 0, stream>>>(
        s, cnt, h1, W2, r2, b2, h2, nullptr, nullptr, N);

    // ---- layer 3: 32 -> 64, no relu, fused max-pool
    (void)hipMemsetAsync(s, 0, (size_t)N * RELS * 32 * 4, stream);
    scatter_kernel<32><<<(E * 32 + 255) / 256, 256, 0, stream>>>(h2, srcp, dstp, et, s, E);
    transform_kernel<32, 64, false, true><<<(N + 255) / 256, 256, 0, stream>>>(
        s, cnt, h2, W3, r3, b3, nullptr, gpool, batch, N);

    // ---- MLP head + softmax
    mlp_kernel<<<NGRAPH, 256, 0, stream>>>(gpool, Wf1, bf1, Wh, bh, Wl, bl, (float*)d_out);
}

// Round 4
// 596.512 us; speedup vs baseline: 9.0178x; 9.0178x over previous
//
#include <hip/hip_runtime.h>

#define RELS 4
#define NGRAPH 256

static inline size_t alignup(size_t x) { return (x + 255) & ~(size_t)255; }

// ---------------------------------------------------------------------------
// Count edges per (dst, relation): cnt[dst*R + et] += 1
// ---------------------------------------------------------------------------
__global__ void count_kernel(const int* __restrict__ dst, const int* __restrict__ et,
                             float* __restrict__ cnt, int E)
{
    int e = blockIdx.x * blockDim.x + threadIdx.x;
    if (e < E) {
        unsafeAtomicAdd(&cnt[dst[e] * RELS + et[e]], 1.0f);
    }
}

// ---------------------------------------------------------------------------
// Scatter-add features into per-(node,relation) accumulator.
// Lane-per-channel: IN consecutive lanes handle one edge's IN channels,
// so atomic addresses are consecutive within each group (L2 locality).
// ---------------------------------------------------------------------------
template<int IN>
__global__ void scatter_kernel(const float* __restrict__ feat,
                               const int* __restrict__ src,
                               const int* __restrict__ dst,
                               const int* __restrict__ et,
                               float* __restrict__ s, int E)
{
    constexpr int SH = (IN == 16) ? 4 : 5;
    int i = blockIdx.x * blockDim.x + threadIdx.x;
    int total = E * IN;
    if (i >= total) return;
    int e = i >> SH;
    int k = i & (IN - 1);
    float v = feat[src[e] * IN + k];
    unsafeAtomicAdd(&s[(dst[e] * RELS + et[e]) * IN + k], v);
}

// ---------------------------------------------------------------------------
// Dense per-node transform (round-1 shape: flat control flow, no spills):
//   out[i] = bias + hin[i] @ root + sum_r (s[i,r]/max(cnt[i,r],1)) @ W_r
// Output goes to hout + node*ostride (layer 3 packs into its own s-slot,
// so s/hout may alias: no __restrict__ on them, per-thread read-then-write).
// ---------------------------------------------------------------------------
template<int IN, int OUT, bool RELU>
__global__ __launch_bounds__(256)
void transform_kernel(const float* s, const float* __restrict__ cnt,
                      const float* __restrict__ hin,
                      const float* __restrict__ W, const float* __restrict__ root,
                      const float* __restrict__ bias,
                      float* hout, int ostride, int n)
{
    constexpr int WSZ = RELS * IN * OUT;   // relation weights
    constexpr int RSZ = IN * OUT;          // root weights
    __shared__ float sW[WSZ + RSZ + OUT];
    for (int i = threadIdx.x; i < WSZ; i += 256) sW[i] = W[i];
    for (int i = threadIdx.x; i < RSZ; i += 256) sW[WSZ + i] = root[i];
    for (int i = threadIdx.x; i < OUT; i += 256) sW[WSZ + RSZ + i] = bias[i];
    __syncthreads();

    int node = (int)blockIdx.x * 256 + (int)threadIdx.x;
    if (node >= n) return;

    const float4* sWv = (const float4*)sW;
    float4 acc[OUT / 4];
    #pragma unroll
    for (int o = 0; o < OUT / 4; ++o) acc[o] = sWv[(WSZ + RSZ) / 4 + o];

    // root term: hin[node] @ root
    const float4* hv = (const float4*)(hin + (size_t)node * IN);
    #pragma unroll
    for (int k4 = 0; k4 < IN / 4; ++k4) {
        float4 xv = hv[k4];
        #pragma unroll
        for (int kk = 0; kk < 4; ++kk) {
            float x1 = (&xv.x)[kk];
            int k = k4 * 4 + kk;
            #pragma unroll
            for (int o = 0; o < OUT / 4; ++o) {
                float4 w = sWv[(WSZ + k * OUT) / 4 + o];
                acc[o].x += x1 * w.x; acc[o].y += x1 * w.y;
                acc[o].z += x1 * w.z; acc[o].w += x1 * w.w;
            }
        }
    }

    // relation terms
    #pragma unroll
    for (int r = 0; r < RELS; ++r) {
        float c = cnt[node * RELS + r];
        float nrm = 1.0f / fmaxf(c, 1.0f);
        const float4* sv = (const float4*)(s + ((size_t)node * RELS + r) * IN);
        #pragma unroll
        for (int k4 = 0; k4 < IN / 4; ++k4) {
            float4 mv = sv[k4];
            mv.x *= nrm; mv.y *= nrm; mv.z *= nrm; mv.w *= nrm;
            #pragma unroll
            for (int kk = 0; kk < 4; ++kk) {
                float m1 = (&mv.x)[kk];
                int k = k4 * 4 + kk;
                #pragma unroll
                for (int o = 0; o < OUT / 4; ++o) {
                    float4 w = sWv[((r * IN + k) * OUT) / 4 + o];
                    acc[o].x += m1 * w.x; acc[o].y += m1 * w.y;
                    acc[o].z += m1 * w.z; acc[o].w += m1 * w.w;
                }
            }
        }
    }

    if (RELU) {
        #pragma unroll
        for (int o = 0; o < OUT / 4; ++o) {
            acc[o].x = fmaxf(acc[o].x, 0.f); acc[o].y = fmaxf(acc[o].y, 0.f);
            acc[o].z = fmaxf(acc[o].z, 0.f); acc[o].w = fmaxf(acc[o].w, 0.f);
        }
    }

    float4* ho = (float4*)(hout + (size_t)node * ostride);
    #pragma unroll
    for (int o = 0; o < OUT / 4; ++o) ho[o] = acc[o];
}

// ---------------------------------------------------------------------------
// Segment-max pool: one block per graph. batch is sorted, so each graph is a
// contiguous node range found by binary search. 64 channels x 4 row-groups,
// register max -> tiny LDS reduce -> plain store. Zero atomics.
// h3 is packed at stride 128 (inside the s buffer).
// ---------------------------------------------------------------------------
__device__ inline int lower_bound_i(const int* a, int n, int key)
{
    int lo = 0, hi = n;
    while (lo < hi) { int mid = (lo + hi) >> 1; if (a[mid] < key) lo = mid + 1; else hi = mid; }
    return lo;
}

__global__ __launch_bounds__(256)
void pool_kernel(const float* __restrict__ h3, const int* __restrict__ batch,
                 float* __restrict__ gpool, int n)
{
    int g = blockIdx.x;
    int t = threadIdx.x;
    int ch = t & 63, q = t >> 6;

    int start = lower_bound_i(batch, n, g);
    int end   = lower_bound_i(batch, n, g + 1);

    float m = -INFINITY;
    for (int r = start + q; r < end; r += 4)
        m = fmaxf(m, h3[(size_t)r * 128 + ch]);

    __shared__ float red[4][64];
    red[q][ch] = m;
    __syncthreads();
    if (q == 0) {
        m = fmaxf(fmaxf(red[0][ch], red[1][ch]), fmaxf(red[2][ch], red[3][ch]));
        gpool[g * 64 + ch] = m;
    }
}

// ---------------------------------------------------------------------------
// MLP head: [G,64] -> 128 (relu) -> 256 (relu) -> 51 -> softmax. 1 block/graph.
// ---------------------------------------------------------------------------
__global__ __launch_bounds__(256)
void mlp_kernel(const float* __restrict__ gpool,
                const float* __restrict__ Wf1, const float* __restrict__ bf1,
                const float* __restrict__ Wh,  const float* __restrict__ bh,
                const float* __restrict__ Wl,  const float* __restrict__ bl,
                float* __restrict__ out)
{
    __shared__ float gin[64];
    __shared__ float f1[128];
    __shared__ float f2[256];
    __shared__ float lg[51];
    int g = blockIdx.x, t = threadIdx.x;

    if (t < 64) gin[t] = gpool[g * 64 + t];
    __syncthreads();

    if (t < 128) {
        float a = bf1[t];
        #pragma unroll 8
        for (int k = 0; k < 64; ++k) a += gin[k] * Wf1[k * 128 + t];
        f1[t] = fmaxf(a, 0.f);
    }
    __syncthreads();

    {
        float a = bh[t];
        #pragma unroll 8
        for (int k = 0; k < 128; ++k) a += f1[k] * Wh[k * 256 + t];
        f2[t] = fmaxf(a, 0.f);
    }
    __syncthreads();

    if (t < 51) {
        float a = bl[t];
        #pragma unroll 8
        for (int k = 0; k < 256; ++k) a += f2[k] * Wl[k * 51 + t];
        lg[t] = a;
    }
    __syncthreads();

    if (t == 0) {
        float m = lg[0];
        for (int i = 1; i < 51; ++i) m = fmaxf(m, lg[i]);
        float ssum = 0.f;
        for (int i = 0; i < 51; ++i) { float e = __expf(lg[i] - m); lg[i] = e; ssum += e; }
        float inv = 1.0f / ssum;
        for (int i = 0; i < 51; ++i) out[g * 51 + i] = lg[i] * inv;
    }
}

// ---------------------------------------------------------------------------
extern "C" void kernel_launch(void* const* d_in, const int* in_sizes, int n_in,
                              void* d_out, int out_size, void* d_ws, size_t ws_size,
                              hipStream_t stream)
{
    const float* x    = (const float*)d_in[0];
    const int*   ei   = (const int*)d_in[1];
    const int*   et   = (const int*)d_in[2];
    const int*   batch= (const int*)d_in[3];
    const float* W1   = (const float*)d_in[4];
    const float* r1   = (const float*)d_in[5];
    const float* b1   = (const float*)d_in[6];
    const float* W2   = (const float*)d_in[7];
    const float* r2   = (const float*)d_in[8];
    const float* b2   = (const float*)d_in[9];
    const float* W3   = (const float*)d_in[10];
    const float* r3   = (const float*)d_in[11];
    const float* b3   = (const float*)d_in[12];
    const float* Wf1  = (const float*)d_in[13];
    const float* bf1  = (const float*)d_in[14];
    const float* Wh   = (const float*)d_in[15];
    const float* bh   = (const float*)d_in[16];
    const float* Wl   = (const float*)d_in[17];
    const float* bl   = (const float*)d_in[18];

    const int N = in_sizes[0] / 16;
    const int E = in_sizes[2];
    const int* srcp = ei;
    const int* dstp = ei + E;

    char* ws = (char*)d_ws;
    size_t off = 0;
    float* s     = (float*)(ws + off);   off += alignup((size_t)N * RELS * 32 * 4);
    float* cnt   = (float*)(ws + off);   off += alignup((size_t)N * RELS * 4);
    float* h1    = (float*)(ws + off);   off += alignup((size_t)N * 16 * 4);
    float* h2    = (float*)(ws + off);   off += alignup((size_t)N * 32 * 4);
    float* gpool = (float*)(ws + off);   off += alignup((size_t)NGRAPH * 64 * 4);
    (void)ws_size; (void)n_in; (void)out_size;

    // zero accumulators (stream-ordered, capture-safe)
    (void)hipMemsetAsync(cnt, 0, (size_t)N * RELS * 4, stream);
    (void)hipMemsetAsync(s, 0, (size_t)N * RELS * 16 * 4, stream);

    count_kernel<<<(E + 255) / 256, 256, 0, stream>>>(dstp, et, cnt, E);

    // ---- layer 1: 16 -> 16, relu
    scatter_kernel<16><<<(E * 16 + 255) / 256, 256, 0, stream>>>(x, srcp, dstp, et, s, E);
    transform_kernel<16, 16, true><<<(N + 255) / 256, 256, 0, stream>>>(
        s, cnt, x, W1, r1, b1, h1, 16, N);

    // ---- layer 2: 16 -> 32, relu
    (void)hipMemsetAsync(s, 0, (size_t)N * RELS * 16 * 4, stream);
    scatter_kernel<16><<<(E * 16 + 255) / 256, 256, 0, stream>>>(h1, srcp, dstp, et, s, E);
    transform_kernel<16, 32, true><<<(N + 255) / 256, 256, 0, stream>>>(
        s, cnt, h1, W2, r2, b2, h2, 32, N);

    // ---- layer 3: 32 -> 64, no relu; pack output into each node's own s-slot
    (void)hipMemsetAsync(s, 0, (size_t)N * RELS * 32 * 4, stream);
    scatter_kernel<32><<<(E * 32 + 255) / 256, 256, 0, stream>>>(h2, srcp, dstp, et, s, E);
    transform_kernel<32, 64, false><<<(N + 255) / 256, 256, 0, stream>>>(
        s, cnt, h2, W3, r3, b3, /*hout=*/s, /*ostride=*/128, N);

    // ---- segment-max pool (no atomics)
    pool_kernel<<<NGRAPH, 256, 0, stream>>>(s, batch, gpool, N);

    // ---- MLP head + softmax
    mlp_kernel<<<NGRAPH, 256, 0, stream>>>(gpool, Wf1, bf1, Wh, bh, Wl, bl, (float*)d_out);
}

// Round 5
// 482.526 us; speedup vs baseline: 11.1481x; 1.2362x over previous
//
#include <hip/hip_runtime.h>

#define RELS 4
#define NGRAPH 256
#define SCAN_BLK 2048   // elements per scan1 block (256 thr x 8)

static inline size_t alignup(size_t x) { return (x + 255) & ~(size_t)255; }

// ---------------------------------------------------------------------------
// CSR build step 1: histogram of segments seg = dst*R + et
// ---------------------------------------------------------------------------
__global__ void hist_kernel(const int* __restrict__ dst, const int* __restrict__ et,
                            int* __restrict__ hcnt, int E)
{
    int e = blockIdx.x * blockDim.x + threadIdx.x;
    if (e < E) atomicAdd(&hcnt[dst[e] * RELS + et[e]], 1);
}

// ---------------------------------------------------------------------------
// CSR build step 2: exclusive scan over NSEG bins (3 kernels)
// ---------------------------------------------------------------------------
__global__ __launch_bounds__(256)
void scan1_kernel(const int* __restrict__ in, int* __restrict__ excl,
                  int* __restrict__ bsum, int n)
{
    __shared__ int lds[256];
    int tid = threadIdx.x;
    int base = blockIdx.x * SCAN_BLK + tid * 8;
    int v[8];
    #pragma unroll
    for (int i = 0; i < 8; ++i) v[i] = (base + i < n) ? in[base + i] : 0;
    int run = 0;
    #pragma unroll
    for (int i = 0; i < 8; ++i) { int t = v[i]; v[i] = run; run += t; }
    lds[tid] = run;
    __syncthreads();
    for (int off = 1; off < 256; off <<= 1) {
        int t = (tid >= off) ? lds[tid - off] : 0;
        __syncthreads();
        lds[tid] += t;
        __syncthreads();
    }
    int ex = (tid > 0) ? lds[tid - 1] : 0;
    if (tid == 255) bsum[blockIdx.x] = lds[255];
    #pragma unroll
    for (int i = 0; i < 8; ++i) if (base + i < n) excl[base + i] = v[i] + ex;
}

__global__ __launch_bounds__(256)
void scan2_kernel(const int* __restrict__ bsum, int* __restrict__ boff, int nb)
{
    __shared__ int lds[256];
    int tid = threadIdx.x;
    lds[tid] = (tid < nb) ? bsum[tid] : 0;
    __syncthreads();
    for (int off = 1; off < 256; off <<= 1) {
        int t = (tid >= off) ? lds[tid - off] : 0;
        __syncthreads();
        lds[tid] += t;
        __syncthreads();
    }
    if (tid < nb) boff[tid] = (tid > 0) ? lds[tid - 1] : 0;
}

__global__ void scan3_kernel(const int* __restrict__ excl, const int* __restrict__ boff,
                             int* __restrict__ ptr, int n, int total)
{
    int i = blockIdx.x * blockDim.x + threadIdx.x;
    if (i < n) ptr[i] = excl[i] + boff[i / SCAN_BLK];
    if (i == 0) ptr[n] = total;
}

// ---------------------------------------------------------------------------
// CSR build step 3: fill sorted src-node list
// ---------------------------------------------------------------------------
__global__ void fill_kernel(const int* __restrict__ src, const int* __restrict__ dst,
                            const int* __restrict__ et, const int* __restrict__ ptr,
                            int* __restrict__ cursor, int* __restrict__ ssrc, int E)
{
    int e = blockIdx.x * blockDim.x + threadIdx.x;
    if (e < E) {
        int seg = dst[e] * RELS + et[e];
        int pos = atomicAdd(&cursor[seg], 1);
        ssrc[ptr[seg] + pos] = src[e];
    }
}

// ---------------------------------------------------------------------------
// Fused RGCN layer: gather (CSR, float4 lanes) + normalize + dense transform.
//   out[i] = bias + hin[i] @ root + sum_r (mean_{e in seg(i,r)} feat[src_e]) @ W_r
// LPN = IN/4 lanes per node; each lane gathers one float4 channel-slice,
// drops aggregates into an LDS tile, then computes OUT/LPN output channels
// reading agg broadcast + weights from LDS. One barrier per kernel.
// ---------------------------------------------------------------------------
template<int IN, int OUT, bool RELU>
__global__ __launch_bounds__(256)
void rgcn_layer_kernel(const float* __restrict__ feat,
                       const int* __restrict__ ptr, const int* __restrict__ ssrc,
                       const float* __restrict__ W, const float* __restrict__ root,
                       const float* __restrict__ bias,
                       float* __restrict__ hout, int n)
{
    constexpr int LPN = IN / 4;          // lanes per node
    constexpr int NPB = 256 / LPN;       // nodes per block
    constexpr int WSZ = RELS * IN * OUT;
    constexpr int RSZ = IN * OUT;
    constexpr int AGS = 5 * IN + 4;      // agg stride (floats), 16B-aligned + bank skew
    constexpr int OPL = OUT / (4 * LPN); // float4 outputs per lane

    __shared__ float sW[WSZ + RSZ + OUT];
    __shared__ float agg[NPB * AGS];

    for (int i = threadIdx.x; i < WSZ; i += 256) sW[i] = W[i];
    for (int i = threadIdx.x; i < RSZ; i += 256) sW[WSZ + i] = root[i];
    for (int i = threadIdx.x; i < OUT; i += 256) sW[WSZ + RSZ + i] = bias[i];

    int nl   = (int)threadIdx.x / LPN;
    int ch4  = (int)threadIdx.x % LPN;
    int node = (int)blockIdx.x * NPB + nl;

    if (node < n) {
        const float4* fv = (const float4*)feat;
        #pragma unroll
        for (int r = 0; r < RELS; ++r) {
            int seg = node * RELS + r;
            int p0 = ptr[seg], p1 = ptr[seg + 1];
            float4 a = {0.f, 0.f, 0.f, 0.f};
            for (int e = p0; e < p1; ++e) {
                int sn = ssrc[e];
                float4 v = fv[sn * LPN + ch4];
                a.x += v.x; a.y += v.y; a.z += v.z; a.w += v.w;
            }
            float nm = 1.0f / fmaxf((float)(p1 - p0), 1.0f);
            a.x *= nm; a.y *= nm; a.z *= nm; a.w *= nm;
            *(float4*)&agg[nl * AGS + r * IN + ch4 * 4] = a;
        }
        // root slot (s = 4): raw input features
        *(float4*)&agg[nl * AGS + 4 * IN + ch4 * 4] = fv[node * LPN + ch4];
    }
    __syncthreads();
    if (node >= n) return;

    const float4* sWv = (const float4*)sW;
    float4 acc[OPL];
    #pragma unroll
    for (int o = 0; o < OPL; ++o) acc[o] = sWv[(WSZ + RSZ) / 4 + ch4 * OPL + o];

    const float* ag = &agg[nl * AGS];
    #pragma unroll 4
    for (int sk = 0; sk < 5 * IN; ++sk) {     // sk = s*IN + k matches sW layout
        float m = ag[sk];
        #pragma unroll
        for (int o = 0; o < OPL; ++o) {
            float4 w = sWv[(sk * OUT) / 4 + ch4 * OPL + o];
            acc[o].x += m * w.x; acc[o].y += m * w.y;
            acc[o].z += m * w.z; acc[o].w += m * w.w;
        }
    }

    if (RELU) {
        #pragma unroll
        for (int o = 0; o < OPL; ++o) {
            acc[o].x = fmaxf(acc[o].x, 0.f); acc[o].y = fmaxf(acc[o].y, 0.f);
            acc[o].z = fmaxf(acc[o].z, 0.f); acc[o].w = fmaxf(acc[o].w, 0.f);
        }
    }

    float4* ho = (float4*)(hout + (size_t)node * OUT);
    #pragma unroll
    for (int o = 0; o < OPL; ++o) ho[ch4 * OPL + o] = acc[o];
}

// ---------------------------------------------------------------------------
// Segment-max pool: one block per graph, contiguous node range via binary
// search on sorted batch. Register max -> LDS reduce -> plain store.
// ---------------------------------------------------------------------------
__device__ inline int lower_bound_i(const int* a, int n, int key)
{
    int lo = 0, hi = n;
    while (lo < hi) { int mid = (lo + hi) >> 1; if (a[mid] < key) lo = mid + 1; else hi = mid; }
    return lo;
}

__global__ __launch_bounds__(256)
void pool_kernel(const float* __restrict__ h3, const int* __restrict__ batch,
                 float* __restrict__ gpool, int n)
{
    int g = blockIdx.x;
    int t = threadIdx.x;
    int ch = t & 63, q = t >> 6;

    int start = lower_bound_i(batch, n, g);
    int end   = lower_bound_i(batch, n, g + 1);

    float m = -INFINITY;
    for (int r = start + q; r < end; r += 4)
        m = fmaxf(m, h3[(size_t)r * 64 + ch]);

    __shared__ float red[4][64];
    red[q][ch] = m;
    __syncthreads();
    if (q == 0) {
        m = fmaxf(fmaxf(red[0][ch], red[1][ch]), fmaxf(red[2][ch], red[3][ch]));
        gpool[g * 64 + ch] = m;
    }
}

// ---------------------------------------------------------------------------
// MLP head: [G,64] -> 128 (relu) -> 256 (relu) -> 51 -> softmax. 1 block/graph.
// ---------------------------------------------------------------------------
__global__ __launch_bounds__(256)
void mlp_kernel(const float* __restrict__ gpool,
                const float* __restrict__ Wf1, const float* __restrict__ bf1,
                const float* __restrict__ Wh,  const float* __restrict__ bh,
                const float* __restrict__ Wl,  const float* __restrict__ bl,
                float* __restrict__ out)
{
    __shared__ float gin[64];
    __shared__ float f1[128];
    __shared__ float f2[256];
    __shared__ float lg[51];
    int g = blockIdx.x, t = threadIdx.x;

    if (t < 64) gin[t] = gpool[g * 64 + t];
    __syncthreads();

    if (t < 128) {
        float a = bf1[t];
        #pragma unroll 8
        for (int k = 0; k < 64; ++k) a += gin[k] * Wf1[k * 128 + t];
        f1[t] = fmaxf(a, 0.f);
    }
    __syncthreads();

    {
        float a = bh[t];
        #pragma unroll 8
        for (int k = 0; k < 128; ++k) a += f1[k] * Wh[k * 256 + t];
        f2[t] = fmaxf(a, 0.f);
    }
    __syncthreads();

    if (t < 51) {
        float a = bl[t];
        #pragma unroll 8
        for (int k = 0; k < 256; ++k) a += f2[k] * Wl[k * 51 + t];
        lg[t] = a;
    }
    __syncthreads();

    if (t == 0) {
        float m = lg[0];
        for (int i = 1; i < 51; ++i) m = fmaxf(m, lg[i]);
        float ssum = 0.f;
        for (int i = 0; i < 51; ++i) { float e = __expf(lg[i] - m); lg[i] = e; ssum += e; }
        float inv = 1.0f / ssum;
        for (int i = 0; i < 51; ++i) out[g * 51 + i] = lg[i] * inv;
    }
}

// ---------------------------------------------------------------------------
extern "C" void kernel_launch(void* const* d_in, const int* in_sizes, int n_in,
                              void* d_out, int out_size, void* d_ws, size_t ws_size,
                              hipStream_t stream)
{
    const float* x    = (const float*)d_in[0];
    const int*   ei   = (const int*)d_in[1];
    const int*   et   = (const int*)d_in[2];
    const int*   batch= (const int*)d_in[3];
    const float* W1   = (const float*)d_in[4];
    const float* r1   = (const float*)d_in[5];
    const float* b1   = (const float*)d_in[6];
    const float* W2   = (const float*)d_in[7];
    const float* r2   = (const float*)d_in[8];
    const float* b2   = (const float*)d_in[9];
    const float* W3   = (const float*)d_in[10];
    const float* r3   = (const float*)d_in[11];
    const float* b3   = (const float*)d_in[12];
    const float* Wf1  = (const float*)d_in[13];
    const float* bf1  = (const float*)d_in[14];
    const float* Wh   = (const float*)d_in[15];
    const float* bh   = (const float*)d_in[16];
    const float* Wl   = (const float*)d_in[17];
    const float* bl   = (const float*)d_in[18];

    const int N = in_sizes[0] / 16;
    const int E = in_sizes[2];
    const int NSEG = N * RELS;
    const int NBLK = (NSEG + SCAN_BLK - 1) / SCAN_BLK;   // 196 for N=100k
    const int* srcp = ei;
    const int* dstp = ei + E;

    char* ws = (char*)d_ws;
    size_t off = 0;
    int*   hcnt   = (int*)(ws + off);   off += alignup((size_t)NSEG * 4);
    int*   ptr    = (int*)(ws + off);   off += alignup((size_t)(NSEG + 1) * 4);
    int*   excl   = (int*)(ws + off);   off += alignup((size_t)NSEG * 4);
    int*   bsum   = (int*)(ws + off);   off += alignup(256 * 4);
    int*   boff   = (int*)(ws + off);   off += alignup(256 * 4);
    int*   cursor = (int*)(ws + off);   off += alignup((size_t)NSEG * 4);
    int*   ssrc   = (int*)(ws + off);   off += alignup((size_t)E * 4);
    float* h1     = (float*)(ws + off); off += alignup((size_t)N * 16 * 4);
    float* h2     = (float*)(ws + off); off += alignup((size_t)N * 32 * 4);
    float* h3     = (float*)(ws + off); off += alignup((size_t)N * 64 * 4);
    float* gpool  = (float*)(ws + off); off += alignup((size_t)NGRAPH * 64 * 4);
    (void)ws_size; (void)n_in; (void)out_size;

    // ---- build CSR (once per call; reused by all 3 layers)
    (void)hipMemsetAsync(hcnt, 0, (size_t)NSEG * 4, stream);
    (void)hipMemsetAsync(cursor, 0, (size_t)NSEG * 4, stream);
    hist_kernel<<<(E + 255) / 256, 256, 0, stream>>>(dstp, et, hcnt, E);
    scan1_kernel<<<NBLK, 256, 0, stream>>>(hcnt, excl, bsum, NSEG);
    scan2_kernel<<<1, 256, 0, stream>>>(bsum, boff, NBLK);
    scan3_kernel<<<(NSEG + 255) / 256, 256, 0, stream>>>(excl, boff, ptr, NSEG, E);
    fill_kernel<<<(E + 255) / 256, 256, 0, stream>>>(srcp, dstp, et, ptr, cursor, ssrc, E);

    // ---- three fused gather+transform layers
    rgcn_layer_kernel<16, 16, true><<<(N + 63) / 64, 256, 0, stream>>>(
        x, ptr, ssrc, W1, r1, b1, h1, N);
    rgcn_layer_kernel<16, 32, true><<<(N + 63) / 64, 256, 0, stream>>>(
        h1, ptr, ssrc, W2, r2, b2, h2, N);
    rgcn_layer_kernel<32, 64, false><<<(N + 31) / 32, 256, 0, stream>>>(
        h2, ptr, ssrc, W3, r3, b3, h3, N);

    // ---- segment-max pool (no atomics)
    pool_kernel<<<NGRAPH, 256, 0, stream>>>(h3, batch, gpool, N);

    // ---- MLP head + softmax
    mlp_kernel<<<NGRAPH, 256, 0, stream>>>(gpool, Wf1, bf1, Wh, bh, Wl, bl, (float*)d_out);
}

// Round 6
// 372.694 us; speedup vs baseline: 14.4334x; 1.2947x over previous
//
#include <hip/hip_runtime.h>

#define RELS 4
#define NGRAPH 256
#define SCAN_BLK 2048   // elements per scan1 block (256 thr x 8)

static inline size_t alignup(size_t x) { return (x + 255) & ~(size_t)255; }

// ---------------------------------------------------------------------------
// CSR build step 1: histogram of segments seg = dst*R + et
// ---------------------------------------------------------------------------
__global__ void hist_kernel(const int* __restrict__ dst, const int* __restrict__ et,
                            int* __restrict__ hcnt, int E)
{
    int e = blockIdx.x * blockDim.x + threadIdx.x;
    if (e < E) atomicAdd(&hcnt[dst[e] * RELS + et[e]], 1);
}

// ---------------------------------------------------------------------------
// CSR build step 2: exclusive scan over NSEG bins (3 kernels)
// ---------------------------------------------------------------------------
__global__ __launch_bounds__(256)
void scan1_kernel(const int* __restrict__ in, int* __restrict__ excl,
                  int* __restrict__ bsum, int n)
{
    __shared__ int lds[256];
    int tid = threadIdx.x;
    int base = blockIdx.x * SCAN_BLK + tid * 8;
    int v[8];
    #pragma unroll
    for (int i = 0; i < 8; ++i) v[i] = (base + i < n) ? in[base + i] : 0;
    int run = 0;
    #pragma unroll
    for (int i = 0; i < 8; ++i) { int t = v[i]; v[i] = run; run += t; }
    lds[tid] = run;
    __syncthreads();
    for (int off = 1; off < 256; off <<= 1) {
        int t = (tid >= off) ? lds[tid - off] : 0;
        __syncthreads();
        lds[tid] += t;
        __syncthreads();
    }
    int ex = (tid > 0) ? lds[tid - 1] : 0;
    if (tid == 255) bsum[blockIdx.x] = lds[255];
    #pragma unroll
    for (int i = 0; i < 8; ++i) if (base + i < n) excl[base + i] = v[i] + ex;
}

__global__ __launch_bounds__(256)
void scan2_kernel(const int* __restrict__ bsum, int* __restrict__ boff, int nb)
{
    __shared__ int lds[256];
    int tid = threadIdx.x;
    lds[tid] = (tid < nb) ? bsum[tid] : 0;
    __syncthreads();
    for (int off = 1; off < 256; off <<= 1) {
        int t = (tid >= off) ? lds[tid - off] : 0;
        __syncthreads();
        lds[tid] += t;
        __syncthreads();
    }
    if (tid < nb) boff[tid] = (tid > 0) ? lds[tid - 1] : 0;
}

__global__ void scan3_kernel(const int* __restrict__ excl, const int* __restrict__ boff,
                             int* __restrict__ ptr, int n, int total)
{
    int i = blockIdx.x * blockDim.x + threadIdx.x;
    if (i < n) ptr[i] = excl[i] + boff[i / SCAN_BLK];
    if (i == 0) ptr[n] = total;
}

// ---------------------------------------------------------------------------
// CSR build step 3: fill sorted src-node list
// ---------------------------------------------------------------------------
__global__ void fill_kernel(const int* __restrict__ src, const int* __restrict__ dst,
                            const int* __restrict__ et, const int* __restrict__ ptr,
                            int* __restrict__ cursor, int* __restrict__ ssrc, int E)
{
    int e = blockIdx.x * blockDim.x + threadIdx.x;
    if (e < E) {
        int seg = dst[e] * RELS + et[e];
        int pos = atomicAdd(&cursor[seg], 1);
        ssrc[ptr[seg] + pos] = src[e];
    }
}

// ---------------------------------------------------------------------------
// Fused RGCN layer: gather (CSR, float4 lanes) + normalize + dense transform.
//   out[i] = bias + hin[i] @ root + sum_r (mean_{e in seg(i,r)} feat[src_e]) @ W_r
// LPN = IN/4 lanes per node; each lane gathers one float4 channel-slice into
// REGISTERS (a[5]; slot 4 = own features for the root term), then the compute
// phase broadcasts slices across the lane group via __shfl — no agg LDS tile,
// no second barrier. Gather loop is 4x unrolled (4 independent feature loads
// in flight); all 5 segment boundaries preloaded per node.
// ---------------------------------------------------------------------------
template<int IN, int OUT, bool RELU>
__global__ __launch_bounds__(256)
void rgcn_layer_kernel(const float* __restrict__ feat,
                       const int* __restrict__ ptr, const int* __restrict__ ssrc,
                       const float* __restrict__ W, const float* __restrict__ root,
                       const float* __restrict__ bias,
                       float* __restrict__ hout, int n)
{
    constexpr int LPN = IN / 4;          // lanes per node
    constexpr int NPB = 256 / LPN;       // nodes per block
    constexpr int WSZ = RELS * IN * OUT;
    constexpr int RSZ = IN * OUT;
    constexpr int OPL = OUT / (4 * LPN); // float4 outputs per lane

    __shared__ float sW[WSZ + RSZ + OUT];
    for (int i = threadIdx.x; i < WSZ; i += 256) sW[i] = W[i];
    for (int i = threadIdx.x; i < RSZ; i += 256) sW[WSZ + i] = root[i];
    for (int i = threadIdx.x; i < OUT; i += 256) sW[WSZ + RSZ + i] = bias[i];
    __syncthreads();

    int nl   = (int)threadIdx.x / LPN;
    int ch4  = (int)threadIdx.x % LPN;
    int node = (int)blockIdx.x * NPB + nl;
    if (node >= n) return;                // whole LPN-group exits together

    const float4* fv = (const float4*)feat;

    // preload all 5 segment boundaries (ptr is 16B-aligned, node*RELS % 4 == 0)
    int4 p4  = *(const int4*)(ptr + (size_t)node * RELS);
    int pend = ptr[(size_t)node * RELS + RELS];
    int pb[RELS + 1] = {p4.x, p4.y, p4.z, p4.w, pend};

    float4 a[RELS + 1];
    #pragma unroll
    for (int r = 0; r < RELS; ++r) {
        int p0 = pb[r], p1 = pb[r + 1];
        float4 ac = {0.f, 0.f, 0.f, 0.f};
        int e = p0;
        for (; e + 4 <= p1; e += 4) {
            int s0 = ssrc[e], s1 = ssrc[e + 1], s2 = ssrc[e + 2], s3 = ssrc[e + 3];
            float4 v0 = fv[(size_t)s0 * LPN + ch4];
            float4 v1 = fv[(size_t)s1 * LPN + ch4];
            float4 v2 = fv[(size_t)s2 * LPN + ch4];
            float4 v3 = fv[(size_t)s3 * LPN + ch4];
            ac.x += (v0.x + v1.x) + (v2.x + v3.x);
            ac.y += (v0.y + v1.y) + (v2.y + v3.y);
            ac.z += (v0.z + v1.z) + (v2.z + v3.z);
            ac.w += (v0.w + v1.w) + (v2.w + v3.w);
        }
        for (; e < p1; ++e) {
            int sn = ssrc[e];
            float4 v = fv[(size_t)sn * LPN + ch4];
            ac.x += v.x; ac.y += v.y; ac.z += v.z; ac.w += v.w;
        }
        float nm = 1.0f / fmaxf((float)(p1 - p0), 1.0f);
        a[r].x = ac.x * nm; a[r].y = ac.y * nm;
        a[r].z = ac.z * nm; a[r].w = ac.w * nm;
    }
    // root slot: own features
    a[RELS] = fv[(size_t)node * LPN + ch4];

    // ---- compute phase: shfl-broadcast agg slices within the lane group
    const float4* sWv = (const float4*)sW;
    float4 acc[OPL];
    #pragma unroll
    for (int o = 0; o < OPL; ++o) acc[o] = sWv[(WSZ + RSZ) / 4 + ch4 * OPL + o];

    int lane  = (int)threadIdx.x & 63;
    int gbase = lane & ~(LPN - 1);

    #pragma unroll
    for (int s = 0; s < RELS + 1; ++s) {
        #pragma unroll
        for (int k4 = 0; k4 < LPN; ++k4) {
            float m0 = __shfl(a[s].x, gbase + k4, 64);
            float m1 = __shfl(a[s].y, gbase + k4, 64);
            float m2 = __shfl(a[s].z, gbase + k4, 64);
            float m3 = __shfl(a[s].w, gbase + k4, 64);
            int sk = s * IN + k4 * 4;   // matches sW layout (s=4 -> root block)
            #pragma unroll
            for (int o = 0; o < OPL; ++o) {
                float4 w0 = sWv[((sk + 0) * OUT) / 4 + ch4 * OPL + o];
                float4 w1 = sWv[((sk + 1) * OUT) / 4 + ch4 * OPL + o];
                float4 w2 = sWv[((sk + 2) * OUT) / 4 + ch4 * OPL + o];
                float4 w3 = sWv[((sk + 3) * OUT) / 4 + ch4 * OPL + o];
                acc[o].x += m0 * w0.x + m1 * w1.x + m2 * w2.x + m3 * w3.x;
                acc[o].y += m0 * w0.y + m1 * w1.y + m2 * w2.y + m3 * w3.y;
                acc[o].z += m0 * w0.z + m1 * w1.z + m2 * w2.z + m3 * w3.z;
                acc[o].w += m0 * w0.w + m1 * w1.w + m2 * w2.w + m3 * w3.w;
            }
        }
    }

    if (RELU) {
        #pragma unroll
        for (int o = 0; o < OPL; ++o) {
            acc[o].x = fmaxf(acc[o].x, 0.f); acc[o].y = fmaxf(acc[o].y, 0.f);
            acc[o].z = fmaxf(acc[o].z, 0.f); acc[o].w = fmaxf(acc[o].w, 0.f);
        }
    }

    float4* ho = (float4*)(hout + (size_t)node * OUT);
    #pragma unroll
    for (int o = 0; o < OPL; ++o) ho[ch4 * OPL + o] = acc[o];
}

// ---------------------------------------------------------------------------
// Segment-max pool: one block per graph, contiguous node range via binary
// search on sorted batch. Register max -> LDS reduce -> plain store.
// ---------------------------------------------------------------------------
__device__ inline int lower_bound_i(const int* a, int n, int key)
{
    int lo = 0, hi = n;
    while (lo < hi) { int mid = (lo + hi) >> 1; if (a[mid] < key) lo = mid + 1; else hi = mid; }
    return lo;
}

__global__ __launch_bounds__(256)
void pool_kernel(const float* __restrict__ h3, const int* __restrict__ batch,
                 float* __restrict__ gpool, int n)
{
    int g = blockIdx.x;
    int t = threadIdx.x;
    int ch = t & 63, q = t >> 6;

    int start = lower_bound_i(batch, n, g);
    int end   = lower_bound_i(batch, n, g + 1);

    float m = -INFINITY;
    for (int r = start + q; r < end; r += 4)
        m = fmaxf(m, h3[(size_t)r * 64 + ch]);

    __shared__ float red[4][64];
    red[q][ch] = m;
    __syncthreads();
    if (q == 0) {
        m = fmaxf(fmaxf(red[0][ch], red[1][ch]), fmaxf(red[2][ch], red[3][ch]));
        gpool[g * 64 + ch] = m;
    }
}

// ---------------------------------------------------------------------------
// MLP head: [G,64] -> 128 (relu) -> 256 (relu) -> 51 -> softmax. 1 block/graph.
// ---------------------------------------------------------------------------
__global__ __launch_bounds__(256)
void mlp_kernel(const float* __restrict__ gpool,
                const float* __restrict__ Wf1, const float* __restrict__ bf1,
                const float* __restrict__ Wh,  const float* __restrict__ bh,
                const float* __restrict__ Wl,  const float* __restrict__ bl,
                float* __restrict__ out)
{
    __shared__ float gin[64];
    __shared__ float f1[128];
    __shared__ float f2[256];
    __shared__ float lg[51];
    int g = blockIdx.x, t = threadIdx.x;

    if (t < 64) gin[t] = gpool[g * 64 + t];
    __syncthreads();

    if (t < 128) {
        float a = bf1[t];
        #pragma unroll 8
        for (int k = 0; k < 64; ++k) a += gin[k] * Wf1[k * 128 + t];
        f1[t] = fmaxf(a, 0.f);
    }
    __syncthreads();

    {
        float a = bh[t];
        #pragma unroll 8
        for (int k = 0; k < 128; ++k) a += f1[k] * Wh[k * 256 + t];
        f2[t] = fmaxf(a, 0.f);
    }
    __syncthreads();

    if (t < 51) {
        float a = bl[t];
        #pragma unroll 8
        for (int k = 0; k < 256; ++k) a += f2[k] * Wl[k * 51 + t];
        lg[t] = a;
    }
    __syncthreads();

    if (t == 0) {
        float m = lg[0];
        for (int i = 1; i < 51; ++i) m = fmaxf(m, lg[i]);
        float ssum = 0.f;
        for (int i = 0; i < 51; ++i) { float e = __expf(lg[i] - m); lg[i] = e; ssum += e; }
        float inv = 1.0f / ssum;
        for (int i = 0; i < 51; ++i) out[g * 51 + i] = lg[i] * inv;
    }
}

// ---------------------------------------------------------------------------
extern "C" void kernel_launch(void* const* d_in, const int* in_sizes, int n_in,
                              void* d_out, int out_size, void* d_ws, size_t ws_size,
                              hipStream_t stream)
{
    const float* x    = (const float*)d_in[0];
    const int*   ei   = (const int*)d_in[1];
    const int*   et   = (const int*)d_in[2];
    const int*   batch= (const int*)d_in[3];
    const float* W1   = (const float*)d_in[4];
    const float* r1   = (const float*)d_in[5];
    const float* b1   = (const float*)d_in[6];
    const float* W2   = (const float*)d_in[7];
    const float* r2   = (const float*)d_in[8];
    const float* b2   = (const float*)d_in[9];
    const float* W3   = (const float*)d_in[10];
    const float* r3   = (const float*)d_in[11];
    const float* b3   = (const float*)d_in[12];
    const float* Wf1  = (const float*)d_in[13];
    const float* bf1  = (const float*)d_in[14];
    const float* Wh   = (const float*)d_in[15];
    const float* bh   = (const float*)d_in[16];
    const float* Wl   = (const float*)d_in[17];
    const float* bl   = (const float*)d_in[18];

    const int N = in_sizes[0] / 16;
    const int E = in_sizes[2];
    const int NSEG = N * RELS;
    const int NBLK = (NSEG + SCAN_BLK - 1) / SCAN_BLK;
    const int* srcp = ei;
    const int* dstp = ei + E;

    char* ws = (char*)d_ws;
    size_t off = 0;
    int*   hcnt   = (int*)(ws + off);   off += alignup((size_t)NSEG * 4);
    int*   ptr    = (int*)(ws + off);   off += alignup((size_t)(NSEG + 1) * 4);
    int*   excl   = (int*)(ws + off);   off += alignup((size_t)NSEG * 4);
    int*   bsum   = (int*)(ws + off);   off += alignup(256 * 4);
    int*   boff   = (int*)(ws + off);   off += alignup(256 * 4);
    int*   cursor = (int*)(ws + off);   off += alignup((size_t)NSEG * 4);
    int*   ssrc   = (int*)(ws + off);   off += alignup((size_t)E * 4);
    float* h1     = (float*)(ws + off); off += alignup((size_t)N * 16 * 4);
    float* h2     = (float*)(ws + off); off += alignup((size_t)N * 32 * 4);
    float* h3     = (float*)(ws + off); off += alignup((size_t)N * 64 * 4);
    float* gpool  = (float*)(ws + off); off += alignup((size_t)NGRAPH * 64 * 4);
    (void)ws_size; (void)n_in; (void)out_size;

    // ---- build CSR (once per call; reused by all 3 layers)
    (void)hipMemsetAsync(hcnt, 0, (size_t)NSEG * 4, stream);
    (void)hipMemsetAsync(cursor, 0, (size_t)NSEG * 4, stream);
    hist_kernel<<<(E + 255) / 256, 256, 0, stream>>>(dstp, et, hcnt, E);
    scan1_kernel<<<NBLK, 256, 0, stream>>>(hcnt, excl, bsum, NSEG);
    scan2_kernel<<<1, 256, 0, stream>>>(bsum, boff, NBLK);
    scan3_kernel<<<(NSEG + 255) / 256, 256, 0, stream>>>(excl, boff, ptr, NSEG, E);
    fill_kernel<<<(E + 255) / 256, 256, 0, stream>>>(srcp, dstp, et, ptr, cursor, ssrc, E);

    // ---- three fused gather+transform layers
    rgcn_layer_kernel<16, 16, true><<<(N + 63) / 64, 256, 0, stream>>>(
        x, ptr, ssrc, W1, r1, b1, h1, N);
    rgcn_layer_kernel<16, 32, true><<<(N + 63) / 64, 256, 0, stream>>>(
        h1, ptr, ssrc, W2, r2, b2, h2, N);
    rgcn_layer_kernel<32, 64, false><<<(N + 31) / 32, 256, 0, stream>>>(
        h2, ptr, ssrc, W3, r3, b3, h3, N);

    // ---- segment-max pool (no atomics)
    pool_kernel<<<NGRAPH, 256, 0, stream>>>(h3, batch, gpool, N);

    // ---- MLP head + softmax
    mlp_kernel<<<NGRAPH, 256, 0, stream>>>(gpool, Wf1, bf1, Wh, bh, Wl, bl, (float*)d_out);
}

// Round 7
// 347.579 us; speedup vs baseline: 15.4762x; 1.0723x over previous
//
#include <hip/hip_runtime.h>

#define RELS 4
#define NGRAPH 256
#define SCAN_BLK 2048   // elements per scan1 block (256 thr x 8)

static inline size_t alignup(size_t x) { return (x + 255) & ~(size_t)255; }

// ---------------------------------------------------------------------------
// CSR build step 1: histogram of segments seg = dst*R + et
// ---------------------------------------------------------------------------
__global__ void hist_kernel(const int* __restrict__ dst, const int* __restrict__ et,
                            int* __restrict__ hcnt, int E)
{
    int e = blockIdx.x * blockDim.x + threadIdx.x;
    if (e < E) atomicAdd(&hcnt[dst[e] * RELS + et[e]], 1);
}

// ---------------------------------------------------------------------------
// CSR build step 2: exclusive scan over NSEG bins (3 kernels)
// ---------------------------------------------------------------------------
__global__ __launch_bounds__(256)
void scan1_kernel(const int* __restrict__ in, int* __restrict__ excl,
                  int* __restrict__ bsum, int n)
{
    __shared__ int lds[256];
    int tid = threadIdx.x;
    int base = blockIdx.x * SCAN_BLK + tid * 8;
    int v[8];
    #pragma unroll
    for (int i = 0; i < 8; ++i) v[i] = (base + i < n) ? in[base + i] : 0;
    int run = 0;
    #pragma unroll
    for (int i = 0; i < 8; ++i) { int t = v[i]; v[i] = run; run += t; }
    lds[tid] = run;
    __syncthreads();
    for (int off = 1; off < 256; off <<= 1) {
        int t = (tid >= off) ? lds[tid - off] : 0;
        __syncthreads();
        lds[tid] += t;
        __syncthreads();
    }
    int ex = (tid > 0) ? lds[tid - 1] : 0;
    if (tid == 255) bsum[blockIdx.x] = lds[255];
    #pragma unroll
    for (int i = 0; i < 8; ++i) if (base + i < n) excl[base + i] = v[i] + ex;
}

__global__ __launch_bounds__(256)
void scan2_kernel(const int* __restrict__ bsum, int* __restrict__ boff, int nb)
{
    __shared__ int lds[256];
    int tid = threadIdx.x;
    lds[tid] = (tid < nb) ? bsum[tid] : 0;
    __syncthreads();
    for (int off = 1; off < 256; off <<= 1) {
        int t = (tid >= off) ? lds[tid - off] : 0;
        __syncthreads();
        lds[tid] += t;
        __syncthreads();
    }
    if (tid < nb) boff[tid] = (tid > 0) ? lds[tid - 1] : 0;
}

__global__ void scan3_kernel(const int* __restrict__ excl, const int* __restrict__ boff,
                             int* __restrict__ ptr, int n, int total)
{
    int i = blockIdx.x * blockDim.x + threadIdx.x;
    if (i < n) ptr[i] = excl[i] + boff[i / SCAN_BLK];
    if (i == 0) ptr[n] = total;
}

// ---------------------------------------------------------------------------
// CSR build step 3: fill sorted src-node list
// ---------------------------------------------------------------------------
__global__ void fill_kernel(const int* __restrict__ src, const int* __restrict__ dst,
                            const int* __restrict__ et, const int* __restrict__ ptr,
                            int* __restrict__ cursor, int* __restrict__ ssrc, int E)
{
    int e = blockIdx.x * blockDim.x + threadIdx.x;
    if (e < E) {
        int seg = dst[e] * RELS + et[e];
        int pos = atomicAdd(&cursor[seg], 1);
        ssrc[ptr[seg] + pos] = src[e];
    }
}

// ---------------------------------------------------------------------------
// Fused RGCN layer, wave-specialized compute:
//  Phase 1 (gather): 4 lanes/node, NPB=64 nodes/block. Each lane gathers its
//  float4 channel slices over the node's 4 CSR segments (4x unrolled loads),
//  normalizes, and writes agg rows to LDS. Row stride K+1 (odd) -> the
//  column-wise b32 reads in phase 2 are bank-conflict-free.
//  Phase 2 (compute): wave w computes output-channel quarter w for all 64
//  nodes (lane = node). Weight row addresses are wave-uniform -> compiler
//  emits s_load (SMEM pipe, SGPR operand in the FMA). Per k: ONE b32 LDS
//  read. This removes all per-node weight traffic from the DS pipe.
// ---------------------------------------------------------------------------
template<int IN, int OUT, bool RELU>
__global__ __launch_bounds__(256)
void rgcn_layer_kernel(const float* __restrict__ feat,
                       const int* __restrict__ ptr, const int* __restrict__ ssrc,
                       const float* __restrict__ W, const float* __restrict__ root,
                       const float* __restrict__ bias,
                       float* __restrict__ hout, int n)
{
    constexpr int NPB  = 64;          // nodes per block
    constexpr int K    = 5 * IN;      // concat agg (4 rels) + root features
    constexpr int AGS  = K + 1;       // odd LDS row stride (conflict-free b32)
    constexpr int NF4  = IN / 16;     // float4 slices per gather lane (1 or 2)
    constexpr int LPN4 = IN / 4;      // float4 per feature row
    constexpr int Q    = OUT / 4;     // channels per wave-quarter

    __shared__ float agg[NPB * AGS];

    const int tid  = (int)threadIdx.x;
    const int nl   = tid >> 2;
    const int c4   = tid & 3;
    const int node = (int)blockIdx.x * NPB + nl;

    // ---- phase 1: gather ----
    if (node < n) {
        const float4* fv = (const float4*)feat;
        int4 p4  = *(const int4*)(ptr + (size_t)node * RELS);
        int pend = ptr[(size_t)node * RELS + RELS];
        int pb[RELS + 1] = {p4.x, p4.y, p4.z, p4.w, pend};
        float* arow = &agg[nl * AGS];

        #pragma unroll
        for (int r = 0; r < RELS; ++r) {
            float4 ac[NF4];
            #pragma unroll
            for (int j = 0; j < NF4; ++j) ac[j] = {0.f, 0.f, 0.f, 0.f};
            int p0 = pb[r], p1 = pb[r + 1];
            int e = p0;
            for (; e + 4 <= p1; e += 4) {
                int s0 = ssrc[e], s1 = ssrc[e + 1], s2 = ssrc[e + 2], s3 = ssrc[e + 3];
                #pragma unroll
                for (int j = 0; j < NF4; ++j) {
                    float4 v0 = fv[(size_t)s0 * LPN4 + c4 + 4 * j];
                    float4 v1 = fv[(size_t)s1 * LPN4 + c4 + 4 * j];
                    float4 v2 = fv[(size_t)s2 * LPN4 + c4 + 4 * j];
                    float4 v3 = fv[(size_t)s3 * LPN4 + c4 + 4 * j];
                    ac[j].x += (v0.x + v1.x) + (v2.x + v3.x);
                    ac[j].y += (v0.y + v1.y) + (v2.y + v3.y);
                    ac[j].z += (v0.z + v1.z) + (v2.z + v3.z);
                    ac[j].w += (v0.w + v1.w) + (v2.w + v3.w);
                }
            }
            for (; e < p1; ++e) {
                int sn = ssrc[e];
                #pragma unroll
                for (int j = 0; j < NF4; ++j) {
                    float4 v = fv[(size_t)sn * LPN4 + c4 + 4 * j];
                    ac[j].x += v.x; ac[j].y += v.y; ac[j].z += v.z; ac[j].w += v.w;
                }
            }
            float nm = 1.0f / fmaxf((float)(p1 - p0), 1.0f);
            #pragma unroll
            for (int j = 0; j < NF4; ++j) {
                int kb = r * IN + (c4 + 4 * j) * 4;
                arow[kb + 0] = ac[j].x * nm;
                arow[kb + 1] = ac[j].y * nm;
                arow[kb + 2] = ac[j].z * nm;
                arow[kb + 3] = ac[j].w * nm;
            }
        }
        // root slot: own features at k = 4*IN ..
        #pragma unroll
        for (int j = 0; j < NF4; ++j) {
            float4 v = fv[(size_t)node * LPN4 + c4 + 4 * j];
            int kb = 4 * IN + (c4 + 4 * j) * 4;
            arow[kb + 0] = v.x; arow[kb + 1] = v.y;
            arow[kb + 2] = v.z; arow[kb + 3] = v.w;
        }
    }
    __syncthreads();

    // ---- phase 2: compute (wave w -> channel quarter w, lane -> node) ----
    const int qw   = __builtin_amdgcn_readfirstlane(tid >> 6);   // 0..3, SGPR
    const int lane = tid & 63;
    const int cn   = (int)blockIdx.x * NPB + lane;

    const float* __restrict__ wq = W    + qw * Q;   // row stride OUT
    const float* __restrict__ rq = root + qw * Q;
    const float* __restrict__ bq = bias + qw * Q;
    const float* arow = &agg[lane * AGS];

    float acc[Q];
    #pragma unroll
    for (int o = 0; o < Q; ++o) acc[o] = bq[o];

    #pragma unroll 4
    for (int k = 0; k < 4 * IN; ++k) {
        float m = arow[k];
        const float* wr = wq + (size_t)k * OUT;     // wave-uniform -> s_load
        #pragma unroll
        for (int o = 0; o < Q; ++o) acc[o] += m * wr[o];
    }
    #pragma unroll 4
    for (int k = 0; k < IN; ++k) {
        float m = arow[4 * IN + k];
        const float* wr = rq + (size_t)k * OUT;     // wave-uniform -> s_load
        #pragma unroll
        for (int o = 0; o < Q; ++o) acc[o] += m * wr[o];
    }

    if (cn < n) {
        float* ho = hout + (size_t)cn * OUT + qw * Q;
        #pragma unroll
        for (int o = 0; o < Q; o += 4) {
            float4 v;
            v.x = RELU ? fmaxf(acc[o + 0], 0.f) : acc[o + 0];
            v.y = RELU ? fmaxf(acc[o + 1], 0.f) : acc[o + 1];
            v.z = RELU ? fmaxf(acc[o + 2], 0.f) : acc[o + 2];
            v.w = RELU ? fmaxf(acc[o + 3], 0.f) : acc[o + 3];
            *(float4*)(ho + o) = v;
        }
    }
}

// ---------------------------------------------------------------------------
// Segment-max pool: one block per graph, contiguous node range via binary
// search on sorted batch. Register max -> LDS reduce -> plain store.
// ---------------------------------------------------------------------------
__device__ inline int lower_bound_i(const int* a, int n, int key)
{
    int lo = 0, hi = n;
    while (lo < hi) { int mid = (lo + hi) >> 1; if (a[mid] < key) lo = mid + 1; else hi = mid; }
    return lo;
}

__global__ __launch_bounds__(256)
void pool_kernel(const float* __restrict__ h3, const int* __restrict__ batch,
                 float* __restrict__ gpool, int n)
{
    int g = blockIdx.x;
    int t = threadIdx.x;
    int ch = t & 63, q = t >> 6;

    int start = lower_bound_i(batch, n, g);
    int end   = lower_bound_i(batch, n, g + 1);

    float m = -INFINITY;
    for (int r = start + q; r < end; r += 4)
        m = fmaxf(m, h3[(size_t)r * 64 + ch]);

    __shared__ float red[4][64];
    red[q][ch] = m;
    __syncthreads();
    if (q == 0) {
        m = fmaxf(fmaxf(red[0][ch], red[1][ch]), fmaxf(red[2][ch], red[3][ch]));
        gpool[g * 64 + ch] = m;
    }
}

// ---------------------------------------------------------------------------
// MLP head: [G,64] -> 128 (relu) -> 256 (relu) -> 51 -> softmax. 1 block/graph.
// ---------------------------------------------------------------------------
__global__ __launch_bounds__(256)
void mlp_kernel(const float* __restrict__ gpool,
                const float* __restrict__ Wf1, const float* __restrict__ bf1,
                const float* __restrict__ Wh,  const float* __restrict__ bh,
                const float* __restrict__ Wl,  const float* __restrict__ bl,
                float* __restrict__ out)
{
    __shared__ float gin[64];
    __shared__ float f1[128];
    __shared__ float f2[256];
    __shared__ float lg[51];
    int g = blockIdx.x, t = threadIdx.x;

    if (t < 64) gin[t] = gpool[g * 64 + t];
    __syncthreads();

    if (t < 128) {
        float a = bf1[t];
        #pragma unroll 8
        for (int k = 0; k < 64; ++k) a += gin[k] * Wf1[k * 128 + t];
        f1[t] = fmaxf(a, 0.f);
    }
    __syncthreads();

    {
        float a = bh[t];
        #pragma unroll 8
        for (int k = 0; k < 128; ++k) a += f1[k] * Wh[k * 256 + t];
        f2[t] = fmaxf(a, 0.f);
    }
    __syncthreads();

    if (t < 51) {
        float a = bl[t];
        #pragma unroll 8
        for (int k = 0; k < 256; ++k) a += f2[k] * Wl[k * 51 + t];
        lg[t] = a;
    }
    __syncthreads();

    if (t == 0) {
        float m = lg[0];
        for (int i = 1; i < 51; ++i) m = fmaxf(m, lg[i]);
        float ssum = 0.f;
        for (int i = 0; i < 51; ++i) { float e = __expf(lg[i] - m); lg[i] = e; ssum += e; }
        float inv = 1.0f / ssum;
        for (int i = 0; i < 51; ++i) out[g * 51 + i] = lg[i] * inv;
    }
}

// ---------------------------------------------------------------------------
extern "C" void kernel_launch(void* const* d_in, const int* in_sizes, int n_in,
                              void* d_out, int out_size, void* d_ws, size_t ws_size,
                              hipStream_t stream)
{
    const float* x    = (const float*)d_in[0];
    const int*   ei   = (const int*)d_in[1];
    const int*   et   = (const int*)d_in[2];
    const int*   batch= (const int*)d_in[3];
    const float* W1   = (const float*)d_in[4];
    const float* r1   = (const float*)d_in[5];
    const float* b1   = (const float*)d_in[6];
    const float* W2   = (const float*)d_in[7];
    const float* r2   = (const float*)d_in[8];
    const float* b2   = (const float*)d_in[9];
    const float* W3   = (const float*)d_in[10];
    const float* r3   = (const float*)d_in[11];
    const float* b3   = (const float*)d_in[12];
    const float* Wf1  = (const float*)d_in[13];
    const float* bf1  = (const float*)d_in[14];
    const float* Wh   = (const float*)d_in[15];
    const float* bh   = (const float*)d_in[16];
    const float* Wl   = (const float*)d_in[17];
    const float* bl   = (const float*)d_in[18];

    const int N = in_sizes[0] / 16;
    const int E = in_sizes[2];
    const int NSEG = N * RELS;
    const int NBLK = (NSEG + SCAN_BLK - 1) / SCAN_BLK;
    const int* srcp = ei;
    const int* dstp = ei + E;

    char* ws = (char*)d_ws;
    size_t off = 0;
    int*   hcnt   = (int*)(ws + off);   off += alignup((size_t)NSEG * 4);
    int*   ptr    = (int*)(ws + off);   off += alignup((size_t)(NSEG + 1) * 4);
    int*   excl   = (int*)(ws + off);   off += alignup((size_t)NSEG * 4);
    int*   bsum   = (int*)(ws + off);   off += alignup(256 * 4);
    int*   boff   = (int*)(ws + off);   off += alignup(256 * 4);
    int*   cursor = (int*)(ws + off);   off += alignup((size_t)NSEG * 4);
    int*   ssrc   = (int*)(ws + off);   off += alignup((size_t)E * 4);
    float* h1     = (float*)(ws + off); off += alignup((size_t)N * 16 * 4);
    float* h2     = (float*)(ws + off); off += alignup((size_t)N * 32 * 4);
    float* h3     = (float*)(ws + off); off += alignup((size_t)N * 64 * 4);
    float* gpool  = (float*)(ws + off); off += alignup((size_t)NGRAPH * 64 * 4);
    (void)ws_size; (void)n_in; (void)out_size;

    // ---- build CSR (once per call; reused by all 3 layers)
    (void)hipMemsetAsync(hcnt, 0, (size_t)NSEG * 4, stream);
    (void)hipMemsetAsync(cursor, 0, (size_t)NSEG * 4, stream);
    hist_kernel<<<(E + 255) / 256, 256, 0, stream>>>(dstp, et, hcnt, E);
    scan1_kernel<<<NBLK, 256, 0, stream>>>(hcnt, excl, bsum, NSEG);
    scan2_kernel<<<1, 256, 0, stream>>>(bsum, boff, NBLK);
    scan3_kernel<<<(NSEG + 255) / 256, 256, 0, stream>>>(excl, boff, ptr, NSEG, E);
    fill_kernel<<<(E + 255) / 256, 256, 0, stream>>>(srcp, dstp, et, ptr, cursor, ssrc, E);

    // ---- three fused gather+transform layers (NPB = 64 nodes/block)
    rgcn_layer_kernel<16, 16, true><<<(N + 63) / 64, 256, 0, stream>>>(
        x, ptr, ssrc, W1, r1, b1, h1, N);
    rgcn_layer_kernel<16, 32, true><<<(N + 63) / 64, 256, 0, stream>>>(
        h1, ptr, ssrc, W2, r2, b2, h2, N);
    rgcn_layer_kernel<32, 64, false><<<(N + 63) / 64, 256, 0, stream>>>(
        h2, ptr, ssrc, W3, r3, b3, h3, N);

    // ---- segment-max pool (no atomics)
    pool_kernel<<<NGRAPH, 256, 0, stream>>>(h3, batch, gpool, N);

    // ---- MLP head + softmax
    mlp_kernel<<<NGRAPH, 256, 0, stream>>>(gpool, Wf1, bf1, Wh, bh, Wl, bl, (float*)d_out);
}

// Round 8
// 326.324 us; speedup vs baseline: 16.4843x; 1.0651x over previous
//
#include <hip/hip_runtime.h>

#define RELS 4
#define NGRAPH 256
#define SCAN_BLK 2048   // elements per scan1 block (256 thr x 8)

static inline size_t alignup(size_t x) { return (x + 255) & ~(size_t)255; }

// ---------------------------------------------------------------------------
// CSR build step 1: histogram of segments seg = dst*R + et
// ---------------------------------------------------------------------------
__global__ void hist_kernel(const int* __restrict__ dst, const int* __restrict__ et,
                            int* __restrict__ hcnt, int E)
{
    int e = blockIdx.x * blockDim.x + threadIdx.x;
    if (e < E) atomicAdd(&hcnt[dst[e] * RELS + et[e]], 1);
}

// ---------------------------------------------------------------------------
// CSR build step 2: exclusive scan over NSEG bins (3 kernels)
// ---------------------------------------------------------------------------
__global__ __launch_bounds__(256)
void scan1_kernel(const int* __restrict__ in, int* __restrict__ excl,
                  int* __restrict__ bsum, int n)
{
    __shared__ int lds[256];
    int tid = threadIdx.x;
    int base = blockIdx.x * SCAN_BLK + tid * 8;
    int v[8];
    #pragma unroll
    for (int i = 0; i < 8; ++i) v[i] = (base + i < n) ? in[base + i] : 0;
    int run = 0;
    #pragma unroll
    for (int i = 0; i < 8; ++i) { int t = v[i]; v[i] = run; run += t; }
    lds[tid] = run;
    __syncthreads();
    for (int off = 1; off < 256; off <<= 1) {
        int t = (tid >= off) ? lds[tid - off] : 0;
        __syncthreads();
        lds[tid] += t;
        __syncthreads();
    }
    int ex = (tid > 0) ? lds[tid - 1] : 0;
    if (tid == 255) bsum[blockIdx.x] = lds[255];
    #pragma unroll
    for (int i = 0; i < 8; ++i) if (base + i < n) excl[base + i] = v[i] + ex;
}

__global__ __launch_bounds__(256)
void scan2_kernel(const int* __restrict__ bsum, int* __restrict__ boff, int nb)
{
    __shared__ int lds[256];
    int tid = threadIdx.x;
    lds[tid] = (tid < nb) ? bsum[tid] : 0;
    __syncthreads();
    for (int off = 1; off < 256; off <<= 1) {
        int t = (tid >= off) ? lds[tid - off] : 0;
        __syncthreads();
        lds[tid] += t;
        __syncthreads();
    }
    if (tid < nb) boff[tid] = (tid > 0) ? lds[tid - 1] : 0;
}

__global__ void scan3_kernel(const int* __restrict__ excl, const int* __restrict__ boff,
                             int* __restrict__ ptr, int n, int total)
{
    int i = blockIdx.x * blockDim.x + threadIdx.x;
    if (i < n) ptr[i] = excl[i] + boff[i / SCAN_BLK];
    if (i == 0) ptr[n] = total;
}

// ---------------------------------------------------------------------------
// CSR build step 3: fill sorted src-node list
// ---------------------------------------------------------------------------
__global__ void fill_kernel(const int* __restrict__ src, const int* __restrict__ dst,
                            const int* __restrict__ et, const int* __restrict__ ptr,
                            int* __restrict__ cursor, int* __restrict__ ssrc, int E)
{
    int e = blockIdx.x * blockDim.x + threadIdx.x;
    if (e < E) {
        int seg = dst[e] * RELS + et[e];
        int pos = atomicAdd(&cursor[seg], 1);
        ssrc[ptr[seg] + pos] = src[e];
    }
}

// ---------------------------------------------------------------------------
// Fused RGCN layer, wave-specialized compute.
//  Phase 1 (gather): 4 lanes/node, NPB=64 nodes/block, 4x-unrolled CSR walk.
//  Only the 4 relation means go to LDS (K = 4*IN, row stride 4*IN+1 -> odd,
//  conflict-free column reads). Root features are NOT staged.
//  Phase 2 (compute): wave w computes output quarter w for all 64 nodes
//  (lane = node). Weight rows are wave-uniform -> s_load (SMEM pipe).
//  Root term reads the lane's own feature row from global (L1-hot: this
//  block's phase 1 just touched it).
//  MINW = min waves/EU hint: caps VGPRs so occupancy isn't register-limited.
// ---------------------------------------------------------------------------
template<int IN, int OUT, bool RELU, int MINW>
__global__ __launch_bounds__(256, MINW)
void rgcn_layer_kernel(const float* __restrict__ feat,
                       const int* __restrict__ ptr, const int* __restrict__ ssrc,
                       const float* __restrict__ W, const float* __restrict__ root,
                       const float* __restrict__ bias,
                       float* __restrict__ hout, int n)
{
    constexpr int NPB  = 64;          // nodes per block
    constexpr int K    = 4 * IN;      // staged: 4 relation means only
    constexpr int AGS  = K + 1;       // odd LDS row stride (conflict-free b32)
    constexpr int NF4  = IN / 16;     // float4 slices per gather lane (1 or 2)
    constexpr int LPN4 = IN / 4;      // float4 per feature row
    constexpr int Q    = OUT / 4;     // channels per wave-quarter

    __shared__ float agg[NPB * AGS];

    const int tid  = (int)threadIdx.x;
    const int nl   = tid >> 2;
    const int c4   = tid & 3;
    const int node = (int)blockIdx.x * NPB + nl;

    const float4* fv = (const float4*)feat;

    // ---- phase 1: gather ----
    if (node < n) {
        int4 p4  = *(const int4*)(ptr + (size_t)node * RELS);
        int pend = ptr[(size_t)node * RELS + RELS];
        int pb[RELS + 1] = {p4.x, p4.y, p4.z, p4.w, pend};
        float* arow = &agg[nl * AGS];

        #pragma unroll
        for (int r = 0; r < RELS; ++r) {
            float4 ac[NF4];
            #pragma unroll
            for (int j = 0; j < NF4; ++j) ac[j] = {0.f, 0.f, 0.f, 0.f};
            int p0 = pb[r], p1 = pb[r + 1];
            int e = p0;
            for (; e + 4 <= p1; e += 4) {
                int s0 = ssrc[e], s1 = ssrc[e + 1], s2 = ssrc[e + 2], s3 = ssrc[e + 3];
                #pragma unroll
                for (int j = 0; j < NF4; ++j) {
                    float4 v0 = fv[(size_t)s0 * LPN4 + c4 + 4 * j];
                    float4 v1 = fv[(size_t)s1 * LPN4 + c4 + 4 * j];
                    float4 v2 = fv[(size_t)s2 * LPN4 + c4 + 4 * j];
                    float4 v3 = fv[(size_t)s3 * LPN4 + c4 + 4 * j];
                    ac[j].x += (v0.x + v1.x) + (v2.x + v3.x);
                    ac[j].y += (v0.y + v1.y) + (v2.y + v3.y);
                    ac[j].z += (v0.z + v1.z) + (v2.z + v3.z);
                    ac[j].w += (v0.w + v1.w) + (v2.w + v3.w);
                }
            }
            for (; e < p1; ++e) {
                int sn = ssrc[e];
                #pragma unroll
                for (int j = 0; j < NF4; ++j) {
                    float4 v = fv[(size_t)sn * LPN4 + c4 + 4 * j];
                    ac[j].x += v.x; ac[j].y += v.y; ac[j].z += v.z; ac[j].w += v.w;
                }
            }
            float nm = 1.0f / fmaxf((float)(p1 - p0), 1.0f);
            #pragma unroll
            for (int j = 0; j < NF4; ++j) {
                int kb = r * IN + (c4 + 4 * j) * 4;
                arow[kb + 0] = ac[j].x * nm;
                arow[kb + 1] = ac[j].y * nm;
                arow[kb + 2] = ac[j].z * nm;
                arow[kb + 3] = ac[j].w * nm;
            }
        }
    }
    __syncthreads();

    // ---- phase 2: compute (wave w -> channel quarter w, lane -> node) ----
    const int qw   = __builtin_amdgcn_readfirstlane(tid >> 6);   // 0..3, SGPR
    const int lane = tid & 63;
    const int cn   = (int)blockIdx.x * NPB + lane;
    const int cnc  = (cn < n) ? cn : (n - 1);                    // clamp for loads

    const float* __restrict__ wq = W    + qw * Q;   // row stride OUT
    const float* __restrict__ rq = root + qw * Q;
    const float* __restrict__ bq = bias + qw * Q;
    const float* arow = &agg[lane * AGS];

    // own feature row (root term) into registers — L1-hot
    float4 own[LPN4];
    #pragma unroll
    for (int j = 0; j < LPN4; ++j) own[j] = fv[(size_t)cnc * LPN4 + j];

    float acc[Q];
    #pragma unroll
    for (int o = 0; o < Q; ++o) acc[o] = bq[o];

    #pragma unroll 4
    for (int k = 0; k < K; ++k) {
        float m = arow[k];
        const float* wr = wq + (size_t)k * OUT;     // wave-uniform -> s_load
        #pragma unroll
        for (int o = 0; o < Q; ++o) acc[o] += m * wr[o];
    }
    #pragma unroll
    for (int j = 0; j < LPN4; ++j) {
        #pragma unroll
        for (int c = 0; c < 4; ++c) {
            float m = (&own[j].x)[c];
            const float* wr = rq + (size_t)(j * 4 + c) * OUT;   // wave-uniform
            #pragma unroll
            for (int o = 0; o < Q; ++o) acc[o] += m * wr[o];
        }
    }

    if (cn < n) {
        float* ho = hout + (size_t)cn * OUT + qw * Q;
        #pragma unroll
        for (int o = 0; o < Q; o += 4) {
            float4 v;
            v.x = RELU ? fmaxf(acc[o + 0], 0.f) : acc[o + 0];
            v.y = RELU ? fmaxf(acc[o + 1], 0.f) : acc[o + 1];
            v.z = RELU ? fmaxf(acc[o + 2], 0.f) : acc[o + 2];
            v.w = RELU ? fmaxf(acc[o + 3], 0.f) : acc[o + 3];
            *(float4*)(ho + o) = v;
        }
    }
}

// ---------------------------------------------------------------------------
// Segment-max pool: one block per graph, contiguous node range via binary
// search on sorted batch. Register max -> LDS reduce -> plain store.
// ---------------------------------------------------------------------------
__device__ inline int lower_bound_i(const int* a, int n, int key)
{
    int lo = 0, hi = n;
    while (lo < hi) { int mid = (lo + hi) >> 1; if (a[mid] < key) lo = mid + 1; else hi = mid; }
    return lo;
}

__global__ __launch_bounds__(256)
void pool_kernel(const float* __restrict__ h3, const int* __restrict__ batch,
                 float* __restrict__ gpool, int n)
{
    int g = blockIdx.x;
    int t = threadIdx.x;
    int ch = t & 63, q = t >> 6;

    int start = lower_bound_i(batch, n, g);
    int end   = lower_bound_i(batch, n, g + 1);

    float m = -INFINITY;
    for (int r = start + q; r < end; r += 4)
        m = fmaxf(m, h3[(size_t)r * 64 + ch]);

    __shared__ float red[4][64];
    red[q][ch] = m;
    __syncthreads();
    if (q == 0) {
        m = fmaxf(fmaxf(red[0][ch], red[1][ch]), fmaxf(red[2][ch], red[3][ch]));
        gpool[g * 64 + ch] = m;
    }
}

// ---------------------------------------------------------------------------
// MLP head: [G,64] -> 128 (relu) -> 256 (relu) -> 51 -> softmax. 1 block/graph.
// ---------------------------------------------------------------------------
__global__ __launch_bounds__(256)
void mlp_kernel(const float* __restrict__ gpool,
                const float* __restrict__ Wf1, const float* __restrict__ bf1,
                const float* __restrict__ Wh,  const float* __restrict__ bh,
                const float* __restrict__ Wl,  const float* __restrict__ bl,
                float* __restrict__ out)
{
    __shared__ float gin[64];
    __shared__ float f1[128];
    __shared__ float f2[256];
    __shared__ float lg[51];
    int g = blockIdx.x, t = threadIdx.x;

    if (t < 64) gin[t] = gpool[g * 64 + t];
    __syncthreads();

    if (t < 128) {
        float a = bf1[t];
        #pragma unroll 8
        for (int k = 0; k < 64; ++k) a += gin[k] * Wf1[k * 128 + t];
        f1[t] = fmaxf(a, 0.f);
    }
    __syncthreads();

    {
        float a = bh[t];
        #pragma unroll 8
        for (int k = 0; k < 128; ++k) a += f1[k] * Wh[k * 256 + t];
        f2[t] = fmaxf(a, 0.f);
    }
    __syncthreads();

    if (t < 51) {
        float a = bl[t];
        #pragma unroll 8
        for (int k = 0; k < 256; ++k) a += f2[k] * Wl[k * 51 + t];
        lg[t] = a;
    }
    __syncthreads();

    if (t == 0) {
        float m = lg[0];
        for (int i = 1; i < 51; ++i) m = fmaxf(m, lg[i]);
        float ssum = 0.f;
        for (int i = 0; i < 51; ++i) { float e = __expf(lg[i] - m); lg[i] = e; ssum += e; }
        float inv = 1.0f / ssum;
        for (int i = 0; i < 51; ++i) out[g * 51 + i] = lg[i] * inv;
    }
}

// ---------------------------------------------------------------------------
extern "C" void kernel_launch(void* const* d_in, const int* in_sizes, int n_in,
                              void* d_out, int out_size, void* d_ws, size_t ws_size,
                              hipStream_t stream)
{
    const float* x    = (const float*)d_in[0];
    const int*   ei   = (const int*)d_in[1];
    const int*   et   = (const int*)d_in[2];
    const int*   batch= (const int*)d_in[3];
    const float* W1   = (const float*)d_in[4];
    const float* r1   = (const float*)d_in[5];
    const float* b1   = (const float*)d_in[6];
    const float* W2   = (const float*)d_in[7];
    const float* r2   = (const float*)d_in[8];
    const float* b2   = (const float*)d_in[9];
    const float* W3   = (const float*)d_in[10];
    const float* r3   = (const float*)d_in[11];
    const float* b3   = (const float*)d_in[12];
    const float* Wf1  = (const float*)d_in[13];
    const float* bf1  = (const float*)d_in[14];
    const float* Wh   = (const float*)d_in[15];
    const float* bh   = (const float*)d_in[16];
    const float* Wl   = (const float*)d_in[17];
    const float* bl   = (const float*)d_in[18];

    const int N = in_sizes[0] / 16;
    const int E = in_sizes[2];
    const int NSEG = N * RELS;
    const int NBLK = (NSEG + SCAN_BLK - 1) / SCAN_BLK;
    const int* srcp = ei;
    const int* dstp = ei + E;

    char* ws = (char*)d_ws;
    size_t off = 0;
    int*   hcnt   = (int*)(ws + off);   off += alignup((size_t)NSEG * 4);
    int*   ptr    = (int*)(ws + off);   off += alignup((size_t)(NSEG + 1) * 4);
    int*   excl   = (int*)(ws + off);   off += alignup((size_t)NSEG * 4);
    int*   bsum   = (int*)(ws + off);   off += alignup(256 * 4);
    int*   boff   = (int*)(ws + off);   off += alignup(256 * 4);
    int*   cursor = (int*)(ws + off);   off += alignup((size_t)NSEG * 4);
    int*   ssrc   = (int*)(ws + off);   off += alignup((size_t)E * 4);
    float* h1     = (float*)(ws + off); off += alignup((size_t)N * 16 * 4);
    float* h2     = (float*)(ws + off); off += alignup((size_t)N * 32 * 4);
    float* h3     = (float*)(ws + off); off += alignup((size_t)N * 64 * 4);
    float* gpool  = (float*)(ws + off); off += alignup((size_t)NGRAPH * 64 * 4);
    (void)ws_size; (void)n_in; (void)out_size;

    // ---- build CSR (once per call; reused by all 3 layers)
    (void)hipMemsetAsync(hcnt, 0, (size_t)NSEG * 4, stream);
    (void)hipMemsetAsync(cursor, 0, (size_t)NSEG * 4, stream);
    hist_kernel<<<(E + 255) / 256, 256, 0, stream>>>(dstp, et, hcnt, E);
    scan1_kernel<<<NBLK, 256, 0, stream>>>(hcnt, excl, bsum, NSEG);
    scan2_kernel<<<1, 256, 0, stream>>>(bsum, boff, NBLK);
    scan3_kernel<<<(NSEG + 255) / 256, 256, 0, stream>>>(excl, boff, ptr, NSEG, E);
    fill_kernel<<<(E + 255) / 256, 256, 0, stream>>>(srcp, dstp, et, ptr, cursor, ssrc, E);

    // ---- three fused gather+transform layers (NPB = 64 nodes/block)
    rgcn_layer_kernel<16, 16, true, 8><<<(N + 63) / 64, 256, 0, stream>>>(
        x, ptr, ssrc, W1, r1, b1, h1, N);
    rgcn_layer_kernel<16, 32, true, 8><<<(N + 63) / 64, 256, 0, stream>>>(
        h1, ptr, ssrc, W2, r2, b2, h2, N);
    rgcn_layer_kernel<32, 64, false, 4><<<(N + 63) / 64, 256, 0, stream>>>(
        h2, ptr, ssrc, W3, r3, b3, h3, N);

    // ---- segment-max pool (no atomics)
    pool_kernel<<<NGRAPH, 256, 0, stream>>>(h3, batch, gpool, N);

    // ---- MLP head + softmax
    mlp_kernel<<<NGRAPH, 256, 0, stream>>>(gpool, Wf1, bf1, Wh, bh, Wl, bl, (float*)d_out);
}